// Round 7
// baseline (2282.010 us; speedup 1.0000x reference)
//
#include <hip/hip_runtime.h>
#include <hip/hip_cooperative_groups.h>

#define HID 2048
#define BAT 512
#define SEQ 128
#define NCLS 10

typedef __attribute__((ext_vector_type(4))) float f32x4;
typedef __attribute__((ext_vector_type(8))) short s16x8;
typedef __attribute__((ext_vector_type(4))) unsigned short u16x4;

__device__ __forceinline__ float bf2f(unsigned short u) {
  union { unsigned int i; float f; } v;
  v.i = ((unsigned int)u) << 16;
  return v.f;
}
__device__ __forceinline__ unsigned short f2bf(float f) {
  union { float f; unsigned int i; } v;
  v.f = f;
  unsigned int u = v.i;
  return (unsigned short)((u + 0x7fffu + ((u >> 16) & 1u)) >> 16);
}

// fp32 -> bf16, 4 elems/thread
__global__ __launch_bounds__(256) void cvt_kernel(const float* __restrict__ src,
                                                  unsigned short* __restrict__ dst,
                                                  int n) {
  int i = (blockIdx.x * 256 + threadIdx.x) * 4;
  if (i + 3 < n) {
    f32x4 v = *(const f32x4*)(src + i);
    u16x4 o;
    o.x = f2bf(v.x);
    o.y = f2bf(v.y);
    o.z = f2bf(v.z);
    o.w = f2bf(v.w);
    *(u16x4*)(dst + i) = o;
  }
}

// x[BAT][SEQ] -> xT[SEQ][BAT]
__global__ __launch_bounds__(256) void xpose_kernel(const float* __restrict__ x,
                                                    float* __restrict__ xT) {
  const int t = blockIdx.x;
  for (int b = threadIdx.x; b < BAT; b += 256)
    xT[t * BAT + b] = x[b * SEQ + t];
}

// default cpol (L1/L2 cached) - for W
__device__ __forceinline__ void gload16(const void* g, void* l) {
  __builtin_amdgcn_global_load_lds(
      (const __attribute__((address_space(1))) unsigned int*)g,
      (__attribute__((address_space(3))) unsigned int*)l, 16, 0, 0);
}
// DEVICE scope (SC1 only, aux=0x10): bypass non-coherent L1/L2, serviced at L3.
// (Round 6 used 0x11 = SYSTEM scope -> coherence point = HBM -> 1.05 GB refetch/step.)
__device__ __forceinline__ void gload16_dev(const void* g, void* l) {
  __builtin_amdgcn_global_load_lds(
      (const __attribute__((address_space(1))) unsigned int*)g,
      (__attribute__((address_space(3))) unsigned int*)l, 16, 0, 0x10);
}

// Persistent RNN, no grid-wide sync, no cache invalidation.
// 8 independent groups of 32 blocks; group g owns batch cols [64g,64g+64).
// Block (id&31) owns m-panel (id&31)*64. Per step: 64x64x2048 GEMM.
// h stores/loads at DEVICE scope (coherence point = L3, shared by all XCDs);
// W stays default-cached (L2-resident: 4 panels = 1 MB per XCD under id%8 mapping).
// Group barrier: relaxed device-scope atomic counter, monotonic target 32*(t+1).
// K-pipeline: ring-4 LDS buffers, 3 tiles in flight, counted vmcnt(8).
__global__ __launch_bounds__(256) void rnn_kernel(
    const unsigned short* __restrict__ W,
    unsigned short* __restrict__ h0,
    unsigned short* __restrict__ h1,
    const float* __restrict__ whx,   // [HID]
    const float* __restrict__ bh,    // [HID]
    const float* __restrict__ xT,    // [SEQ][BAT]
    unsigned int* __restrict__ cnt) {
  __shared__ unsigned short ldsA[4][64 * 64];
  __shared__ unsigned short ldsB[4][64 * 64];

  const int tid = threadIdx.x;
  const int wave = tid >> 6;
  const int lane = tid & 63;
  const int id = blockIdx.x;
  const int g = id >> 5;            // group 0..7 (batch slice)
  const int m0 = (id & 31) * 64;    // m-panel
  const int n0 = g * 64;            // batch cols
  const int wm = wave >> 1;
  const int wn = wave & 1;
  const int fl = lane & 15;
  const int hi = lane >> 4;

  // staging geometry (thread covers linear dest byte tid*16 of each 32-row half)
  const int r0 = tid >> 3;             // 0..31
  const int r1 = 32 + r0;
  const int c0 = (tid & 7) ^ (r0 & 7); // involution pre-swizzle of source chunk
  const int c1 = (tid & 7) ^ (r1 & 7);
  const unsigned short* gA0 = W + (size_t)(m0 + r0) * HID + c0 * 8;
  const unsigned short* gA1 = W + (size_t)(m0 + r1) * HID + c1 * 8;
  const size_t bo0 = (size_t)(n0 + r0) * HID + c0 * 8;
  const size_t bo1 = (size_t)(n0 + r1) * HID + c1 * 8;
  const int ldst = wave * 512;  // wave-uniform LDS dest offset (shorts)

  // swizzled fragment read offsets
  int offA[2][2], offB[2][2];
#pragma unroll
  for (int f = 0; f < 2; ++f) {
#pragma unroll
    for (int ks = 0; ks < 2; ++ks) {
      const int ra = wm * 32 + f * 16 + fl;
      const int rb = wn * 32 + f * 16 + fl;
      const int ch = ks * 4 + hi;
      offA[f][ks] = ra * 64 + ((ch ^ (ra & 7)) * 8);
      offB[f][ks] = rb * 64 + ((ch ^ (rb & 7)) * 8);
    }
  }

  // t-invariant epilogue constants
  const int mbase = m0 + wm * 32;
  const int nbase = n0 + wn * 32;
  f32x4 wxv[2], bvv[2];
#pragma unroll
  for (int mf = 0; mf < 2; ++mf) {
    wxv[mf] = *(const f32x4*)&whx[mbase + mf * 16 + hi * 4];
    bvv[mf] = *(const f32x4*)&bh[mbase + mf * 16 + hi * 4];
  }

  unsigned short* const A0 = ldsA[0]; unsigned short* const B0 = ldsB[0];
  unsigned short* const A1 = ldsA[1]; unsigned short* const B1 = ldsB[1];
  unsigned short* const A2 = ldsA[2]; unsigned short* const B2 = ldsB[2];
  unsigned short* const A3 = ldsA[3]; unsigned short* const B3 = ldsB[3];

#define STAGE(kk, ab, bb)                        \
  do {                                           \
    gload16(gA0 + (kk), (ab) + ldst);            \
    gload16(gA1 + (kk), (ab) + 2048 + ldst);     \
    gload16_dev(gB0 + (kk), (bb) + ldst);        \
    gload16_dev(gB1 + (kk), (bb) + 2048 + ldst); \
  } while (0)

#define COMPUTE(ab, bb)                                                                  \
  do {                                                                                   \
    _Pragma("unroll") for (int ks = 0; ks < 2; ++ks) {                                   \
      s16x8 a0 = *(const s16x8*)&(ab)[offA[0][ks]];                                      \
      s16x8 a1 = *(const s16x8*)&(ab)[offA[1][ks]];                                      \
      s16x8 b0 = *(const s16x8*)&(bb)[offB[0][ks]];                                      \
      s16x8 b1 = *(const s16x8*)&(bb)[offB[1][ks]];                                      \
      acc[0][0] = __builtin_amdgcn_mfma_f32_16x16x32_bf16(a0, b0, acc[0][0], 0, 0, 0);   \
      acc[0][1] = __builtin_amdgcn_mfma_f32_16x16x32_bf16(a0, b1, acc[0][1], 0, 0, 0);   \
      acc[1][0] = __builtin_amdgcn_mfma_f32_16x16x32_bf16(a1, b0, acc[1][0], 0, 0, 0);   \
      acc[1][1] = __builtin_amdgcn_mfma_f32_16x16x32_bf16(a1, b1, acc[1][1], 0, 0, 0);   \
    }                                                                                    \
  } while (0)

#define WAITB(n) \
  asm volatile("s_waitcnt vmcnt(" #n ") lgkmcnt(0)\n\ts_barrier" ::: "memory")

  for (int t = 0; t < SEQ; ++t) {
    const unsigned short* hin = (t & 1) ? h1 : h0;
    unsigned short* hout = (t & 1) ? h0 : h1;
    const unsigned short* gB0 = hin + bo0;
    const unsigned short* gB1 = hin + bo1;

    f32x4 acc[2][2] = {};

    // prologue: tiles 0,1,2 in flight (12 loads); wait tile 0 (8 left)
    STAGE(0, A0, B0);
    STAGE(64, A1, B1);
    STAGE(128, A2, B2);
    WAITB(8);

    // steady: compute tile k, stage tile k+3, keep 2 stages (8 loads) in flight
#pragma unroll 1
    for (int kb = 0; kb < 28; kb += 4) {
      const int k4 = kb * 64;
      STAGE(k4 + 192, A3, B3); COMPUTE(A0, B0); WAITB(8);
      STAGE(k4 + 256, A0, B0); COMPUTE(A1, B1); WAITB(8);
      STAGE(k4 + 320, A1, B1); COMPUTE(A2, B2); WAITB(8);
      STAGE(k4 + 384, A2, B2); COMPUTE(A3, B3); WAITB(8);
    }
    // tail: tiles 28..31 (tile 31 staged here into slot 3)
    STAGE(1984, A3, B3);
    COMPUTE(A0, B0); WAITB(8);   // tile 28; tile 29 ready
    COMPUTE(A1, B1); WAITB(4);   // tile 29; tile 30 ready
    COMPUTE(A2, B2); WAITB(0);   // tile 30; tile 31 ready
    COMPUTE(A3, B3);             // tile 31

    // epilogue: C/D layout col(n)=lane&15, row(m)=hi*4+j; h store at DEVICE scope
#pragma unroll
    for (int mf = 0; mf < 2; ++mf) {
      const int mrow = mbase + mf * 16 + hi * 4;
#pragma unroll
      for (int nf = 0; nf < 2; ++nf) {
        const int ncol = nbase + nf * 16 + fl;
        const float xv = xT[t * BAT + ncol];
        u16x4 o;
#pragma unroll
        for (int j = 0; j < 4; ++j) {
          float z = acc[mf][nf][j] + wxv[mf][j] * xv + bvv[mf][j];
          o[j] = f2bf(tanhf(z));
        }
        union { u16x4 v; unsigned long long u; } pun;
        pun.v = o;
        const unsigned long long addr =
            (unsigned long long)&hout[(size_t)ncol * HID + mrow];
        asm volatile("global_store_dwordx2 %0, %1, off sc1"
                     :: "v"(addr), "v"(pun.u) : "memory");
      }
    }

    if (t != SEQ - 1) {
      // all waves drain their device-scope stores (retired at L3)
      asm volatile("s_waitcnt vmcnt(0)" ::: "memory");
      __syncthreads();
      if (tid == 0) {
        __hip_atomic_fetch_add(&cnt[g * 16], 1u, __ATOMIC_RELAXED,
                               __HIP_MEMORY_SCOPE_AGENT);
        const unsigned int target = 32u * (unsigned)(t + 1);
        while (__hip_atomic_load(&cnt[g * 16], __ATOMIC_RELAXED,
                                 __HIP_MEMORY_SCOPE_AGENT) < target)
          __builtin_amdgcn_s_sleep(1);
      }
      __syncthreads();
    }
  }
#undef STAGE
#undef COMPUTE
#undef WAITB
}

// out[b][c] = sum_k wp[c][k] * hT[b][k] + bp[c]
__global__ __launch_bounds__(256) void proj_kernel(const unsigned short* __restrict__ hT,
                                                   const float* __restrict__ wp,
                                                   const float* __restrict__ bp,
                                                   float* __restrict__ out) {
  const int b = blockIdx.x;
  const int wave = threadIdx.x >> 6;
  const int lane = threadIdx.x & 63;
  for (int c = wave; c < NCLS; c += 4) {
    float s = 0.f;
    for (int k = lane * 8; k < HID; k += 512) {
      s16x8 hv = *(const s16x8*)&hT[b * HID + k];
      f32x4 w0 = *(const f32x4*)&wp[c * HID + k];
      f32x4 w1 = *(const f32x4*)&wp[c * HID + k + 4];
      s += w0.x * bf2f((unsigned short)hv[0]) + w0.y * bf2f((unsigned short)hv[1]) +
           w0.z * bf2f((unsigned short)hv[2]) + w0.w * bf2f((unsigned short)hv[3]) +
           w1.x * bf2f((unsigned short)hv[4]) + w1.y * bf2f((unsigned short)hv[5]) +
           w1.z * bf2f((unsigned short)hv[6]) + w1.w * bf2f((unsigned short)hv[7]);
    }
#pragma unroll
    for (int off = 32; off > 0; off >>= 1) s += __shfl_down(s, off);
    if (lane == 0) out[b * NCLS + c] = s + bp[c];
  }
}

extern "C" void kernel_launch(void* const* d_in, const int* in_sizes, int n_in,
                              void* d_out, int out_size, void* d_ws, size_t ws_size,
                              hipStream_t stream) {
  (void)in_sizes; (void)n_in; (void)out_size; (void)ws_size;
  const float* x   = (const float*)d_in[0];  // [BAT][SEQ]
  const float* whx = (const float*)d_in[1];  // [HID][1]
  const float* whh = (const float*)d_in[2];  // [HID][HID]
  const float* bh  = (const float*)d_in[3];  // [HID][1]
  const float* wp  = (const float*)d_in[4];  // [NCLS][HID]
  const float* bp  = (const float*)d_in[5];  // [NCLS][1]
  float* out = (float*)d_out;                // [BAT][NCLS]

  unsigned short* Wb = (unsigned short*)d_ws;          // 8 MiB
  unsigned short* h0 = Wb + (size_t)HID * HID;         // 2 MiB
  unsigned short* h1 = h0 + (size_t)BAT * HID;         // 2 MiB
  float* xT = (float*)(h1 + (size_t)BAT * HID);        // 256 KiB
  unsigned int* cnt = (unsigned int*)(xT + (size_t)SEQ * BAT);  // 8 ctrs, 64B stride

  cvt_kernel<<<dim3((HID * HID) / 1024), 256, 0, stream>>>(whh, Wb, HID * HID);
  xpose_kernel<<<dim3(SEQ), 256, 0, stream>>>(x, xT);
  hipMemsetAsync(h0, 0, (size_t)BAT * HID * sizeof(unsigned short), stream);
  hipMemsetAsync(cnt, 0, 8 * 64, stream);

  const unsigned short* Wb_c = Wb;
  unsigned short* h0_p = h0;
  unsigned short* h1_p = h1;
  const float* whx_p = whx;
  const float* bh_p = bh;
  const float* xT_p = xT;
  unsigned int* cnt_p = cnt;
  void* args[] = {(void*)&Wb_c, (void*)&h0_p, (void*)&h1_p,
                  (void*)&whx_p, (void*)&bh_p, (void*)&xT_p, (void*)&cnt_p};
  hipLaunchCooperativeKernel((const void*)rnn_kernel, dim3(256), dim3(256),
                             args, 0, stream);

  // t=127 (odd) wrote h0
  proj_kernel<<<dim3(BAT), 256, 0, stream>>>(h0, wp, bp, out);
}

// Round 8
// 1891.182 us; speedup vs baseline: 1.2067x; 1.2067x over previous
//
#include <hip/hip_runtime.h>
#include <hip/hip_cooperative_groups.h>

#define HID 2048
#define BAT 512
#define SEQ 128
#define NCLS 10

typedef __attribute__((ext_vector_type(4))) float f32x4;
typedef __attribute__((ext_vector_type(8))) short s16x8;
typedef __attribute__((ext_vector_type(4))) unsigned short u16x4;

__device__ __forceinline__ float bf2f(unsigned short u) {
  union { unsigned int i; float f; } v;
  v.i = ((unsigned int)u) << 16;
  return v.f;
}
__device__ __forceinline__ unsigned short f2bf(float f) {
  union { float f; unsigned int i; } v;
  v.f = f;
  unsigned int u = v.i;
  return (unsigned short)((u + 0x7fffu + ((u >> 16) & 1u)) >> 16);
}

// fp32 -> bf16, 4 elems/thread
__global__ __launch_bounds__(256) void cvt_kernel(const float* __restrict__ src,
                                                  unsigned short* __restrict__ dst,
                                                  int n) {
  int i = (blockIdx.x * 256 + threadIdx.x) * 4;
  if (i + 3 < n) {
    f32x4 v = *(const f32x4*)(src + i);
    u16x4 o;
    o.x = f2bf(v.x);
    o.y = f2bf(v.y);
    o.z = f2bf(v.z);
    o.w = f2bf(v.w);
    *(u16x4*)(dst + i) = o;
  }
}

// x[BAT][SEQ] -> xT[SEQ][BAT]
__global__ __launch_bounds__(256) void xpose_kernel(const float* __restrict__ x,
                                                    float* __restrict__ xT) {
  const int t = blockIdx.x;
  for (int b = threadIdx.x; b < BAT; b += 256)
    xT[t * BAT + b] = x[b * SEQ + t];
}

// default cpol (L1/L2 cached) - for W
__device__ __forceinline__ void gload16(const void* g, void* l) {
  __builtin_amdgcn_global_load_lds(
      (const __attribute__((address_space(1))) unsigned int*)g,
      (__attribute__((address_space(3))) unsigned int*)l, 16, 0, 0);
}
// device scope (SC1, aux=0x10): bypass non-coherent L1/L2, serviced at L3 - for h
__device__ __forceinline__ void gload16_dev(const void* g, void* l) {
  __builtin_amdgcn_global_load_lds(
      (const __attribute__((address_space(1))) unsigned int*)g,
      (__attribute__((address_space(3))) unsigned int*)l, 16, 0, 0x10);
}

// Persistent RNN. 8 independent groups of 32 blocks; group g owns batch cols
// [64g,64g+64); block (id&31) owns m-panel. Per step: 64x64x2048 GEMM.
// ROUND 8 CHANGE: ring-8 LDS pipeline (was ring-4). 7 K-tiles (28 loads/wave)
// in flight, steady-state s_waitcnt vmcnt(24): lookahead ~7 iters (~2600 cy)
// covers the ~900 cy L3 latency that rounds 4-7 exposed every iteration.
// h at device scope (L3-coherent); W default-cached. Group barrier: relaxed
// agent-scope atomic counter, monotonic target 32*(t+1).
__global__ __launch_bounds__(256) void rnn_kernel(
    const unsigned short* __restrict__ W,
    unsigned short* __restrict__ h0,
    unsigned short* __restrict__ h1,
    const float* __restrict__ whx,   // [HID]
    const float* __restrict__ bh,    // [HID]
    const float* __restrict__ xT,    // [SEQ][BAT]
    unsigned int* __restrict__ cnt) {
  __shared__ unsigned short ldsA[8][64 * 64];
  __shared__ unsigned short ldsB[8][64 * 64];

  const int tid = threadIdx.x;
  const int wave = tid >> 6;
  const int lane = tid & 63;
  const int id = blockIdx.x;
  const int g = id >> 5;            // group 0..7 (batch slice)
  const int m0 = (id & 31) * 64;    // m-panel
  const int n0 = g * 64;            // batch cols
  const int wm = wave >> 1;
  const int wn = wave & 1;
  const int fl = lane & 15;
  const int hi = lane >> 4;

  // staging geometry (thread covers linear dest byte tid*16 of each 32-row half)
  const int r0 = tid >> 3;             // 0..31
  const int r1 = 32 + r0;
  const int c0 = (tid & 7) ^ (r0 & 7); // involution pre-swizzle of source chunk
  const int c1 = (tid & 7) ^ (r1 & 7);
  const unsigned short* gA0 = W + (size_t)(m0 + r0) * HID + c0 * 8;
  const unsigned short* gA1 = W + (size_t)(m0 + r1) * HID + c1 * 8;
  const size_t bo0 = (size_t)(n0 + r0) * HID + c0 * 8;
  const size_t bo1 = (size_t)(n0 + r1) * HID + c1 * 8;
  const int ldst = wave * 512;  // wave-uniform LDS dest offset (shorts)

  // swizzled fragment read offsets
  int offA[2][2], offB[2][2];
#pragma unroll
  for (int f = 0; f < 2; ++f) {
#pragma unroll
    for (int ks = 0; ks < 2; ++ks) {
      const int ra = wm * 32 + f * 16 + fl;
      const int rb = wn * 32 + f * 16 + fl;
      const int ch = ks * 4 + hi;
      offA[f][ks] = ra * 64 + ((ch ^ (ra & 7)) * 8);
      offB[f][ks] = rb * 64 + ((ch ^ (rb & 7)) * 8);
    }
  }

  // t-invariant epilogue constants
  const int mbase = m0 + wm * 32;
  const int nbase = n0 + wn * 32;
  f32x4 wxv[2], bvv[2];
#pragma unroll
  for (int mf = 0; mf < 2; ++mf) {
    wxv[mf] = *(const f32x4*)&whx[mbase + mf * 16 + hi * 4];
    bvv[mf] = *(const f32x4*)&bh[mbase + mf * 16 + hi * 4];
  }

  unsigned short* const A0 = ldsA[0]; unsigned short* const B0 = ldsB[0];
  unsigned short* const A1 = ldsA[1]; unsigned short* const B1 = ldsB[1];
  unsigned short* const A2 = ldsA[2]; unsigned short* const B2 = ldsB[2];
  unsigned short* const A3 = ldsA[3]; unsigned short* const B3 = ldsB[3];
  unsigned short* const A4 = ldsA[4]; unsigned short* const B4 = ldsB[4];
  unsigned short* const A5 = ldsA[5]; unsigned short* const B5 = ldsB[5];
  unsigned short* const A6 = ldsA[6]; unsigned short* const B6 = ldsB[6];
  unsigned short* const A7 = ldsA[7]; unsigned short* const B7 = ldsB[7];

#define STAGE(kk, ab, bb)                        \
  do {                                           \
    gload16(gA0 + (kk), (ab) + ldst);            \
    gload16(gA1 + (kk), (ab) + 2048 + ldst);     \
    gload16_dev(gB0 + (kk), (bb) + ldst);        \
    gload16_dev(gB1 + (kk), (bb) + 2048 + ldst); \
  } while (0)

#define COMPUTE(ab, bb)                                                                  \
  do {                                                                                   \
    _Pragma("unroll") for (int ks = 0; ks < 2; ++ks) {                                   \
      s16x8 a0 = *(const s16x8*)&(ab)[offA[0][ks]];                                      \
      s16x8 a1 = *(const s16x8*)&(ab)[offA[1][ks]];                                      \
      s16x8 b0 = *(const s16x8*)&(bb)[offB[0][ks]];                                      \
      s16x8 b1 = *(const s16x8*)&(bb)[offB[1][ks]];                                      \
      acc[0][0] = __builtin_amdgcn_mfma_f32_16x16x32_bf16(a0, b0, acc[0][0], 0, 0, 0);   \
      acc[0][1] = __builtin_amdgcn_mfma_f32_16x16x32_bf16(a0, b1, acc[0][1], 0, 0, 0);   \
      acc[1][0] = __builtin_amdgcn_mfma_f32_16x16x32_bf16(a1, b0, acc[1][0], 0, 0, 0);   \
      acc[1][1] = __builtin_amdgcn_mfma_f32_16x16x32_bf16(a1, b1, acc[1][1], 0, 0, 0);   \
    }                                                                                    \
  } while (0)

#define WAITB(n) \
  asm volatile("s_waitcnt vmcnt(" #n ") lgkmcnt(0)\n\ts_barrier" ::: "memory")

  for (int t = 0; t < SEQ; ++t) {
    const unsigned short* hin = (t & 1) ? h1 : h0;
    unsigned short* hout = (t & 1) ? h0 : h1;
    const unsigned short* gB0 = hin + bo0;
    const unsigned short* gB1 = hin + bo1;

    f32x4 acc[2][2] = {};

    // prologue: tiles 0..6 in flight (28 loads/wave); wait tile 0 (24 left)
    STAGE(0 * 64, A0, B0);
    STAGE(1 * 64, A1, B1);
    STAGE(2 * 64, A2, B2);
    STAGE(3 * 64, A3, B3);
    STAGE(4 * 64, A4, B4);
    STAGE(5 * 64, A5, B5);
    STAGE(6 * 64, A6, B6);
    WAITB(24);

    // steady: compute tile ki (slot ki%8), stage tile ki+7 (slot (ki+7)%8),
    // keep 7 stages (28 loads) in flight, retire oldest with vmcnt(24)
#pragma unroll 1
    for (int kb = 0; kb < 3; ++kb) {
      const int k0 = kb * 512;  // elems: kb*8 tiles * 64
      STAGE(k0 + 7 * 64, A7, B7);  COMPUTE(A0, B0); WAITB(24);
      STAGE(k0 + 8 * 64, A0, B0);  COMPUTE(A1, B1); WAITB(24);
      STAGE(k0 + 9 * 64, A1, B1);  COMPUTE(A2, B2); WAITB(24);
      STAGE(k0 + 10 * 64, A2, B2); COMPUTE(A3, B3); WAITB(24);
      STAGE(k0 + 11 * 64, A3, B3); COMPUTE(A4, B4); WAITB(24);
      STAGE(k0 + 12 * 64, A4, B4); COMPUTE(A5, B5); WAITB(24);
      STAGE(k0 + 13 * 64, A5, B5); COMPUTE(A6, B6); WAITB(24);
      STAGE(k0 + 14 * 64, A6, B6); COMPUTE(A7, B7); WAITB(24);
    }
    // ki=24: stage last tile 31 (slot 7), compute 24 (slot 0)
    STAGE(31 * 64, A7, B7); COMPUTE(A0, B0); WAITB(24);
    // tail: tiles 25..31 (slots 1..7), draining 4 loads per tile
    COMPUTE(A1, B1); WAITB(20);
    COMPUTE(A2, B2); WAITB(16);
    COMPUTE(A3, B3); WAITB(12);
    COMPUTE(A4, B4); WAITB(8);
    COMPUTE(A5, B5); WAITB(4);
    COMPUTE(A6, B6); WAITB(0);
    COMPUTE(A7, B7);

    // epilogue: C/D layout col(n)=lane&15, row(m)=hi*4+j; h store at device scope
#pragma unroll
    for (int mf = 0; mf < 2; ++mf) {
      const int mrow = mbase + mf * 16 + hi * 4;
#pragma unroll
      for (int nf = 0; nf < 2; ++nf) {
        const int ncol = nbase + nf * 16 + fl;
        const float xv = xT[t * BAT + ncol];
        u16x4 o;
#pragma unroll
        for (int j = 0; j < 4; ++j) {
          float z = acc[mf][nf][j] + wxv[mf][j] * xv + bvv[mf][j];
          o[j] = f2bf(tanhf(z));
        }
        union { u16x4 v; unsigned long long u; } pun;
        pun.v = o;
        const unsigned long long addr =
            (unsigned long long)&hout[(size_t)ncol * HID + mrow];
        asm volatile("global_store_dwordx2 %0, %1, off sc1"
                     :: "v"(addr), "v"(pun.u) : "memory");
      }
    }

    if (t != SEQ - 1) {
      // all waves drain their device-scope stores (retired at L3)
      asm volatile("s_waitcnt vmcnt(0)" ::: "memory");
      __syncthreads();
      if (tid == 0) {
        __hip_atomic_fetch_add(&cnt[g * 16], 1u, __ATOMIC_RELAXED,
                               __HIP_MEMORY_SCOPE_AGENT);
        const unsigned int target = 32u * (unsigned)(t + 1);
        while (__hip_atomic_load(&cnt[g * 16], __ATOMIC_RELAXED,
                                 __HIP_MEMORY_SCOPE_AGENT) < target)
          __builtin_amdgcn_s_sleep(1);
      }
      __syncthreads();
    }
  }
#undef STAGE
#undef COMPUTE
#undef WAITB
}

// out[b][c] = sum_k wp[c][k] * hT[b][k] + bp[c]
__global__ __launch_bounds__(256) void proj_kernel(const unsigned short* __restrict__ hT,
                                                   const float* __restrict__ wp,
                                                   const float* __restrict__ bp,
                                                   float* __restrict__ out) {
  const int b = blockIdx.x;
  const int wave = threadIdx.x >> 6;
  const int lane = threadIdx.x & 63;
  for (int c = wave; c < NCLS; c += 4) {
    float s = 0.f;
    for (int k = lane * 8; k < HID; k += 512) {
      s16x8 hv = *(const s16x8*)&hT[b * HID + k];
      f32x4 w0 = *(const f32x4*)&wp[c * HID + k];
      f32x4 w1 = *(const f32x4*)&wp[c * HID + k + 4];
      s += w0.x * bf2f((unsigned short)hv[0]) + w0.y * bf2f((unsigned short)hv[1]) +
           w0.z * bf2f((unsigned short)hv[2]) + w0.w * bf2f((unsigned short)hv[3]) +
           w1.x * bf2f((unsigned short)hv[4]) + w1.y * bf2f((unsigned short)hv[5]) +
           w1.z * bf2f((unsigned short)hv[6]) + w1.w * bf2f((unsigned short)hv[7]);
    }
#pragma unroll
    for (int off = 32; off > 0; off >>= 1) s += __shfl_down(s, off);
    if (lane == 0) out[b * NCLS + c] = s + bp[c];
  }
}

extern "C" void kernel_launch(void* const* d_in, const int* in_sizes, int n_in,
                              void* d_out, int out_size, void* d_ws, size_t ws_size,
                              hipStream_t stream) {
  (void)in_sizes; (void)n_in; (void)out_size; (void)ws_size;
  const float* x   = (const float*)d_in[0];  // [BAT][SEQ]
  const float* whx = (const float*)d_in[1];  // [HID][1]
  const float* whh = (const float*)d_in[2];  // [HID][HID]
  const float* bh  = (const float*)d_in[3];  // [HID][1]
  const float* wp  = (const float*)d_in[4];  // [NCLS][HID]
  const float* bp  = (const float*)d_in[5];  // [NCLS][1]
  float* out = (float*)d_out;                // [BAT][NCLS]

  unsigned short* Wb = (unsigned short*)d_ws;          // 8 MiB
  unsigned short* h0 = Wb + (size_t)HID * HID;         // 2 MiB
  unsigned short* h1 = h0 + (size_t)BAT * HID;         // 2 MiB
  float* xT = (float*)(h1 + (size_t)BAT * HID);        // 256 KiB
  unsigned int* cnt = (unsigned int*)(xT + (size_t)SEQ * BAT);  // 8 ctrs, 64B stride

  cvt_kernel<<<dim3((HID * HID) / 1024), 256, 0, stream>>>(whh, Wb, HID * HID);
  xpose_kernel<<<dim3(SEQ), 256, 0, stream>>>(x, xT);
  hipMemsetAsync(h0, 0, (size_t)BAT * HID * sizeof(unsigned short), stream);
  hipMemsetAsync(cnt, 0, 8 * 64, stream);

  const unsigned short* Wb_c = Wb;
  unsigned short* h0_p = h0;
  unsigned short* h1_p = h1;
  const float* whx_p = whx;
  const float* bh_p = bh;
  const float* xT_p = xT;
  unsigned int* cnt_p = cnt;
  void* args[] = {(void*)&Wb_c, (void*)&h0_p, (void*)&h1_p,
                  (void*)&whx_p, (void*)&bh_p, (void*)&xT_p, (void*)&cnt_p};
  hipLaunchCooperativeKernel((const void*)rnn_kernel, dim3(256), dim3(256),
                             args, 0, stream);

  // t=127 (odd) wrote h0
  proj_kernel<<<dim3(BAT), 256, 0, stream>>>(h0, wp, bp, out);
}